// Round 12
// baseline (210.298 us; speedup 1.0000x reference)
//
#include <hip/hip_runtime.h>

#define NN 50000
#define NE 800000
#define NT 3125        // NN/16 mfma tiles
#define NBK 256        // coarse buckets (256 -> k_place uses ALL CUs)
#define BNODE 196      // nodes per bucket (196*256 = 50176 >= NN)
#define BCAP 4096      // bucket capacity (mean 3125, +17 sigma)
#define SCAP 26        // per-block LDS stage capacity per bucket (mean 12.2)
#define BINBLK 256     // bin-part blocks in k_prepbin
#define PREPBLK 64     // prep-part blocks in k_prepbin

typedef __attribute__((ext_vector_type(8))) short short8x;
typedef __attribute__((ext_vector_type(4))) float f32x4;
typedef __attribute__((ext_vector_type(2))) int int2e;
typedef __attribute__((ext_vector_type(2))) unsigned uint2e;

// ws layout (float-index offsets)
#define OFF_ROW   ((long long)NN)     // NN+1 ints (row_ptr)
#define OFF_RECS  (3LL*NN + 16)       // NE int2
#define OFF_FLAGS (35LL*NN + 16)      // ints
#define OFF_PK    (35LL*NN + 256)     // 15360 ushorts (16B-aligned)
#define OFF_FB1S  (35LL*NN + 7936)    // 64 f32
#define OFF_FB2S  (35LL*NN + 8000)    // 32 f32
#define OFF_F1    (36LL*NN)           // binbuf lives here (8 MB < 16 MB region)
#define OFF_F2    (116LL*NN)          // NN*96 bf16
#define OFF_Y2B   (164LL*NN)          // NN*32 bf16
#define OFF_BCUR  (212LL*NN)          // 256 ints

__device__ __forceinline__ float ldf(const void* p, long long i, int bf16) {
  if (bf16) {
    unsigned short u = ((const unsigned short*)p)[i];
    return __uint_as_float(((unsigned)u) << 16);
  }
  return ((const float*)p)[i];
}
__device__ __forceinline__ unsigned short f2bf(float f) {
  unsigned u = __float_as_uint(f);
  unsigned r = (u + 0x7fffu + ((u >> 16) & 1u)) >> 16;
  return (unsigned short)r;
}
__device__ __forceinline__ unsigned pk2(float lo, float hi) {
  return (unsigned)f2bf(lo) | ((unsigned)f2bf(hi) << 16);
}
__device__ __forceinline__ int ldidx(const void* p, long long i, int i64) {
  return i64 ? (int)((const long long*)p)[i] : ((const int*)p)[i];
}
__device__ __forceinline__ float bflo(unsigned u) { return __uint_as_float(u << 16); }
__device__ __forceinline__ float bfhi(unsigned u) { return __uint_as_float(u & 0xffff0000u); }

// ---------------- merged: blocks [0,256) = edge binning; blocks [256,320) = weight prep ----------------
__global__ __launch_bounds__(256) void k_prepbin(
    const void* __restrict__ ei, const void* __restrict__ x,
    const void* __restrict__ W1_msg, const void* __restrict__ b1_msg,
    const void* __restrict__ W1_self, const void* __restrict__ b1_self,
    const void* __restrict__ gamma, const void* __restrict__ beta,
    const void* __restrict__ mean, const void* __restrict__ var,
    const void* __restrict__ W2_msg, const void* __restrict__ b2_msg,
    const void* __restrict__ W2_self, const void* __restrict__ b2_self,
    int* __restrict__ flags, unsigned short* __restrict__ PK,
    float* __restrict__ fb1s, float* __restrict__ fb2s,
    int* __restrict__ bcur, int2* __restrict__ binbuf) {
  int tid = threadIdx.x;
  int lane = tid & 63;
  if (blockIdx.x < BINBLK) {
    // ---- bin body (i64 computed locally; no dependence on flags) ----
    __shared__ int2 stage[NBK][SCAP];  // 53.2 KB
    __shared__ int scnt[NBK];
    __shared__ int gbase[NBK];
    __shared__ int s_i64;
    for (int i = tid; i < NBK; i += 256) scnt[i] = 0;
    if (tid < 64) {
      const int* p = (const int*)ei;
      int any = 0;
      for (int i = lane; i < 256; i += 64) any |= p[2 * i + 1];
      unsigned long long anyb = __ballot(any != 0);
      if (lane == 0) s_i64 = (anyb == 0ull) ? 1 : 0;
    }
    __syncthreads();
    int i64 = s_i64;
    for (long long e0 = (long long)blockIdx.x * 256; e0 < NE;
         e0 += (long long)BINBLK * 256) {
      long long e = e0 + tid;
      if (e < NE) {
        int src = ldidx(ei, e, i64);
        int dst = ldidx(ei, NE + e, i64);
        int b = dst / BNODE;
        int dl = dst - b * BNODE;
        int2 ent = make_int2(src | (dl << 16), (int)e);
        int pos = atomicAdd(&scnt[b], 1);
        if (pos < SCAP) {
          stage[b][pos] = ent;
        } else {  // rare overflow: direct global placement
          int gp = atomicAdd(&bcur[b], 1);
          binbuf[(long long)b * BCAP + gp] = ent;
        }
      }
    }
    __syncthreads();
    if (tid < NBK) {
      int cb = scnt[tid] < SCAP ? scnt[tid] : SCAP;
      gbase[tid] = atomicAdd(&bcur[tid], cb);
    }
    __syncthreads();
    // flush parallelized across the 4 waves
    int wv = tid >> 6, ln = tid & 63;
    for (int b = wv; b < NBK; b += 4) {
      int cb = scnt[b] < SCAP ? scnt[b] : SCAP;
      int gb = gbase[b];
      for (int i = ln; i < cb; i += 64)
        binbuf[(long long)b * BCAP + gb + i] = stage[b][i];
    }
  } else {
    // ---- prep body (runs concurrently with bin; first prep block publishes flags) ----
    __shared__ int s_bf;
    if (tid < 64) {
      const unsigned short* q = (const unsigned short*)x;
      int cntc = 0;
      for (int i = lane; i < 256; i += 64) {
        unsigned short w = q[2 * i];
        int e = (w >> 7) & 0xff;
        if (w == 0 || (e >= 110 && e <= 140)) cntc++;
      }
      for (int m = 1; m < 64; m <<= 1) cntc += __shfl_xor(cntc, m, 64);
      int bfv = (cntc >= 192) ? 1 : 0;
      if (blockIdx.x == BINBLK) {
        const int* p = (const int*)ei;
        int any = 0;
        for (int i = lane; i < 256; i += 64) any |= p[2 * i + 1];
        unsigned long long anyb = __ballot(any != 0);
        if (lane == 0) {
          flags[0] = (anyb == 0ull) ? 1 : 0;
          flags[1] = bfv;
        }
      }
      if (lane == 0) s_bf = bfv;
    }
    __syncthreads();
    int bf = s_bf;
    int t0 = (blockIdx.x - BINBLK) * 256 + tid;
    int stride = PREPBLK * 256;
    for (int i = t0; i < 10240; i += stride) {
      int j = i & 7, L = (i >> 3) & 63, t = (i >> 9) & 3, c = i >> 11;
      int k = c * 32 + ((L >> 4) << 3) + j;
      int col = t * 16 + (L & 15);
      float sc = ldf(gamma, col, bf) * rsqrtf(ldf(var, col, bf) + 1e-5f);
      float v;
      if (k < 64) v = ldf(W1_msg, k * 64 + col, bf) * sc;
      else if (k < 128) v = ldf(W1_self, (k - 64) * 64 + col, bf) * sc;
      else if (k < 144) v = ldf(W1_msg, (64 + k - 128) * 64 + col, bf) * sc;
      else if (k == 144) v = ldf(b1_msg, col, bf) * sc;
      else v = 0.0f;
      PK[i] = f2bf(v);
    }
    for (int i = t0; i < 2048; i += stride) {
      int j = i & 7, L = (i >> 3) & 63, t = (i >> 9) & 1, c = i >> 10;
      int k = c * 32 + ((L >> 4) << 3) + j;
      int col = t * 16 + (L & 15);
      PK[10240 + i] = f2bf(ldf(W2_msg, k * 32 + col, bf));
    }
    for (int i = t0; i < 3072; i += stride) {
      int j = i & 7, L = (i >> 3) & 63, t = (i >> 9) & 1, c = i >> 10;
      int k = c * 32 + ((L >> 4) << 3) + j;
      int col = t * 16 + (L & 15);
      float v;
      if (k < 64) v = ldf(W2_self, k * 32 + col, bf);
      else if (k < 80) v = ldf(W2_msg, k * 32 + col, bf);
      else if (k == 80) v = ldf(b2_msg, col, bf);
      else v = 0.0f;
      PK[12288 + i] = f2bf(v);
    }
    for (int i = t0; i < 64; i += stride) {
      float sc = ldf(gamma, i, bf) * rsqrtf(ldf(var, i, bf) + 1e-5f);
      fb1s[i] = ldf(b1_self, i, bf) * sc + ldf(beta, i, bf) - ldf(mean, i, bf) * sc;
    }
    for (int i = t0; i < 32; i += stride) fb2s[i] = ldf(b2_self, i, bf);
  }
}

// ---------------- phase 2: prefix + histogram + scan + row_ptr + placement ----------------
__global__ __launch_bounds__(1024) void k_place(const int* __restrict__ bcur,
                                                const int2* __restrict__ binbuf,
                                                int* __restrict__ row_ptr,
                                                int2* __restrict__ recs) {
  __shared__ int2 outb[BCAP];  // 32 KB
  __shared__ int lh[BNODE];
  __shared__ int lexc[BNODE];
  __shared__ int lcur[BNODE];
  __shared__ int sb[NBK];
  __shared__ int s_rbase;
  int b = blockIdx.x;
  int tid = threadIdx.x;
  int base = b * BNODE;
  int nn = NN - base < BNODE ? NN - base : BNODE;
  if (tid < NBK) sb[tid] = bcur[tid];
  for (int i = tid; i < BNODE; i += 1024) lh[i] = 0;
  __syncthreads();
  // rbase = exclusive prefix of bucket totals (4 strides of 64 lanes over 256 buckets)
  if (tid < 64) {
    int v = 0;
#pragma unroll
    for (int s = 0; s < 4; ++s) {
      int k = tid + s * 64;
      v += (k < b ? sb[k] : 0);
    }
    for (int off = 32; off > 0; off >>= 1) v += __shfl_down(v, off, 64);
    if (tid == 0) s_rbase = v;
  }
  int cnt = sb[b];
  __syncthreads();
  int rbase = s_rbase;
  // pass 1: local degree histogram
  for (int i = tid; i < cnt; i += 1024) {
    int dl = (binbuf[(long long)b * BCAP + i].x >> 16) & 0x3FF;
    atomicAdd(&lh[dl], 1);
  }
  __syncthreads();
  // wave-0 exclusive scan of lh[0..nn) -> lexc (4 chunks of 64 via shfl)
  if (tid < 64) {
    int carry = 0;
    for (int c0 = 0; c0 < BNODE; c0 += 64) {
      int i = c0 + tid;
      int orig = (i < nn) ? lh[i] : 0;
      int v = orig;
      for (int off = 1; off < 64; off <<= 1) {
        int u = __shfl_up(v, off, 64);
        if (tid >= off) v += u;
      }
      if (i < nn) lexc[i] = carry + v - orig;
      carry += __shfl(v, 63, 64);
    }
  }
  __syncthreads();
  // write row_ptr for this bucket; init placement cursors
  for (int i = tid; i < nn; i += 1024) {
    int e = lexc[i];
    row_ptr[base + i] = rbase + e;
    lcur[i] = e;
  }
  if (b == NBK - 1 && tid == 0) row_ptr[NN] = rbase + cnt;
  __syncthreads();
  // pass 2: placement into LDS at final local offsets
  for (int i = tid; i < cnt; i += 1024) {
    int2 ent = binbuf[(long long)b * BCAP + i];
    int dl = (ent.x >> 16) & 0x3FF;
    int p = atomicAdd(&lcur[dl], 1);
    outb[p] = make_int2(ent.x & 0xFFFF, ent.y);
  }
  __syncthreads();
  // flush: coalesced write of sorted records
  for (int i = tid; i < cnt; i += 1024) recs[rbase + i] = outb[i];
}

// ---------------- fused gather1 + gemm1: 2 waves/tile; gather -> LDS F1-row -> MFMA ----------------
// Gather loop is the proven round-2 body (58 µs floor — do not touch).
__global__ __launch_bounds__(256) void k_gg1(
    const void* __restrict__ x, const void* __restrict__ ea,
    const int* __restrict__ row_ptr, const int2* __restrict__ recs,
    const int* __restrict__ flags, const unsigned short* __restrict__ PK,
    const float* __restrict__ fb1s, unsigned short* __restrict__ F2,
    unsigned short* __restrict__ Y2B) {
  __shared__ __align__(16) unsigned short fs[2][16][168];  // F1-rows, stride 336B (conflict-light)
  __shared__ __align__(16) unsigned short hsh[2][16 * 72]; // h transpose staging
  int tid = threadIdx.x;
  int lane = tid & 63;
  int wv = tid >> 6;
  int tp = wv >> 1, th = wv & 1;
  long long tile = (long long)blockIdx.x * 2 + tp;
  int valid = tile < NT;
  int bf = flags[1];
  int m = lane & 15, quad = lane >> 4;
  if (valid) {
    int g = lane >> 3, c = lane & 7;
    int n = (int)(tile * 16 + th * 8 + g);
    int beg = row_ptr[n];
    int deg = row_ptr[n + 1] - beg;
    float a0 = 0.f, a1 = 0.f, a2 = 0.f, a3 = 0.f, a4 = 0.f, a5 = 0.f, a6 = 0.f, a7 = 0.f;
    float e0 = 0.f, e1 = 0.f, e2 = 0.f, e3 = 0.f;
    uint4 xw;
    if (bf) {
      const unsigned short* xs = (const unsigned short*)x;
      const unsigned short* es = (const unsigned short*)ea;
      int t = 0;
      for (; t + 4 <= deg; t += 4) {
        int2 r0 = recs[beg + t + 0];
        int2 r1 = recs[beg + t + 1];
        int2 r2 = recs[beg + t + 2];
        int2 r3 = recs[beg + t + 3];
        uint4 w0 = *((const uint4*)(xs + ((long long)r0.x << 6)) + c);
        uint4 w1 = *((const uint4*)(xs + ((long long)r1.x << 6)) + c);
        uint4 w2 = *((const uint4*)(xs + ((long long)r2.x << 6)) + c);
        uint4 w3 = *((const uint4*)(xs + ((long long)r3.x << 6)) + c);
        a0 += bflo(w0.x) + bflo(w1.x) + bflo(w2.x) + bflo(w3.x);
        a1 += bfhi(w0.x) + bfhi(w1.x) + bfhi(w2.x) + bfhi(w3.x);
        a2 += bflo(w0.y) + bflo(w1.y) + bflo(w2.y) + bflo(w3.y);
        a3 += bfhi(w0.y) + bfhi(w1.y) + bfhi(w2.y) + bfhi(w3.y);
        a4 += bflo(w0.z) + bflo(w1.z) + bflo(w2.z) + bflo(w3.z);
        a5 += bfhi(w0.z) + bfhi(w1.z) + bfhi(w2.z) + bfhi(w3.z);
        a6 += bflo(w0.w) + bflo(w1.w) + bflo(w2.w) + bflo(w3.w);
        a7 += bfhi(w0.w) + bfhi(w1.w) + bfhi(w2.w) + bfhi(w3.w);
        if (c < 4) {
          uint2 q0 = *((const uint2*)(es + ((long long)r0.y << 4)) + c);
          uint2 q1 = *((const uint2*)(es + ((long long)r1.y << 4)) + c);
          uint2 q2 = *((const uint2*)(es + ((long long)r2.y << 4)) + c);
          uint2 q3 = *((const uint2*)(es + ((long long)r3.y << 4)) + c);
          e0 += bflo(q0.x) + bflo(q1.x) + bflo(q2.x) + bflo(q3.x);
          e1 += bfhi(q0.x) + bfhi(q1.x) + bfhi(q2.x) + bfhi(q3.x);
          e2 += bflo(q0.y) + bflo(q1.y) + bflo(q2.y) + bflo(q3.y);
          e3 += bfhi(q0.y) + bfhi(q1.y) + bfhi(q2.y) + bfhi(q3.y);
        }
      }
      for (; t < deg; ++t) {
        int2 r = recs[beg + t];
        uint4 w = *((const uint4*)(xs + ((long long)r.x << 6)) + c);
        a0 += bflo(w.x); a1 += bfhi(w.x);
        a2 += bflo(w.y); a3 += bfhi(w.y);
        a4 += bflo(w.z); a5 += bfhi(w.z);
        a6 += bflo(w.w); a7 += bfhi(w.w);
        if (c < 4) {
          uint2 q = *((const uint2*)(es + ((long long)r.y << 4)) + c);
          e0 += bflo(q.x); e1 += bfhi(q.x);
          e2 += bflo(q.y); e3 += bfhi(q.y);
        }
      }
      xw = *((const uint4*)(xs + ((long long)n << 6)) + c);
    } else {
      const float* xf = (const float*)x;
      const float* ef = (const float*)ea;
      for (int t = 0; t < deg; ++t) {
        int2 r = recs[beg + t];
        float4 w0 = *((const float4*)(xf + ((long long)r.x << 6)) + c * 2);
        float4 w1 = *((const float4*)(xf + ((long long)r.x << 6)) + c * 2 + 1);
        a0 += w0.x; a1 += w0.y; a2 += w0.z; a3 += w0.w;
        a4 += w1.x; a5 += w1.y; a6 += w1.z; a7 += w1.w;
        if (c < 4) {
          float4 q = *((const float4*)(ef + ((long long)r.y << 4)) + c);
          e0 += q.x; e1 += q.y; e2 += q.z; e3 += q.w;
        }
      }
      float4 p0 = *((const float4*)(xf + ((long long)n << 6)) + c * 2);
      float4 p1 = *((const float4*)(xf + ((long long)n << 6)) + c * 2 + 1);
      xw = make_uint4(pk2(p0.x, p0.y), pk2(p0.z, p0.w), pk2(p1.x, p1.y), pk2(p1.z, p1.w));
    }
    unsigned short* f1 = &fs[tp][th * 8 + g][0];
    unsigned short* f2 = F2 + (long long)n * 96;
    *((uint4*)f1 + c) = make_uint4(pk2(a0, a1), pk2(a2, a3), pk2(a4, a5), pk2(a6, a7));
    *((uint4*)(f1 + 64) + c) = xw;
    if (c < 4) {
      uint2 sp = make_uint2(pk2(e0, e1), pk2(e2, e3));
      *((uint2*)(f1 + 128) + c) = sp;
      *((uint2*)(f2 + 64) + c) = sp;
    }
    if (c == 4) {
      unsigned d = (unsigned)f2bf((float)deg);
      *((uint4*)(f1 + 144)) = make_uint4(d, 0u, 0u, 0u);
      *((uint4*)(f2 + 80)) = make_uint4(d, 0u, 0u, 0u);
    }
    if (c == 5) {
      *((uint4*)(f1 + 152)) = make_uint4(0u, 0u, 0u, 0u);
      *((uint4*)(f2 + 88)) = make_uint4(0u, 0u, 0u, 0u);
    }
  }
  __syncthreads();
  if (valid) {
    long long n0 = tile * 16;
    const unsigned short* f1 = &fs[tp][m][quad * 8];
    short8x A[5];
#pragma unroll
    for (int cc = 0; cc < 5; ++cc) A[cc] = *(const short8x*)(f1 + cc * 32);
    short8x Bf[10];
#pragma unroll
    for (int cc = 0; cc < 5; ++cc)
#pragma unroll
      for (int j = 0; j < 2; ++j)
        Bf[cc * 2 + j] = *(const short8x*)(PK + ((cc * 4 + th * 2 + j) * 64 + lane) * 8);
    f32x4 acc[2];
#pragma unroll
    for (int j = 0; j < 2; ++j) {
      float b = fb1s[(th * 2 + j) * 16 + m];
      acc[j] = (f32x4){b, b, b, b};
    }
#pragma unroll
    for (int cc = 0; cc < 5; ++cc)
#pragma unroll
      for (int j = 0; j < 2; ++j)
        acc[j] = __builtin_amdgcn_mfma_f32_16x16x32_bf16(A[cc], Bf[cc * 2 + j], acc[j], 0, 0, 0);
    // write h to F2 (plain, stays in L2 for gg2) and stage into shared hsh for Y-gemm
    unsigned short* hs = hsh[tp];
#pragma unroll
    for (int j = 0; j < 2; ++j) {
#pragma unroll
      for (int i = 0; i < 4; ++i) {
        float h = fmaxf(acc[j][i], 0.0f);
        unsigned short us = f2bf(h);
        F2[(n0 + quad * 4 + i) * 96 + (th * 2 + j) * 16 + m] = us;
        hs[(quad * 4 + i) * 72 + (th * 2 + j) * 16 + m] = us;
      }
    }
  }
  __syncthreads();
  if (valid) {
    long long n0 = tile * 16;
    const unsigned short* hs = hsh[tp];
    f32x4 yacc = (f32x4){0.f, 0.f, 0.f, 0.f};
#pragma unroll
    for (int cc = 0; cc < 2; ++cc) {
      short8x Ah = *(const short8x*)(hs + m * 72 + cc * 32 + quad * 8);
      short8x By = *(const short8x*)(PK + 10240 + ((cc * 2 + th) * 64 + lane) * 8);
      yacc = __builtin_amdgcn_mfma_f32_16x16x32_bf16(Ah, By, yacc, 0, 0, 0);
    }
#pragma unroll
    for (int i = 0; i < 4; ++i)
      Y2B[(n0 + quad * 4 + i) * 32 + th * 16 + m] = f2bf(yacc[i]);
  }
}

// ---------------- fused gather2 + gemm2 ----------------
// NT loads on the STREAMING inputs (recs, F2) only: Y2B (3.2 MB) fits a 4 MB per-XCD L2,
// but the 16 MB of stream traffic evicts it — NT keeps the gather's target L2-resident.
// Stores stay plain (round-1 lesson: NT stores on sub-line fragments amplify WRITE_SIZE).
__global__ __launch_bounds__(256) void k_gg2(
    const unsigned short* __restrict__ F2, const unsigned short* __restrict__ PK,
    const float* __restrict__ fb2s, const unsigned short* __restrict__ Y2B,
    const int* __restrict__ row_ptr, const int2* __restrict__ recs,
    const int* __restrict__ flags, void* __restrict__ out) {
  __shared__ float sums[2][16][33];  // [tile-pair][row][32ch padded]
  int tid = threadIdx.x;
  int lane = tid & 63;
  int wv = tid >> 6;
  int tp = wv >> 1;
  int th = wv & 1;
  long long tile = (long long)blockIdx.x * 2 + tp;
  int valid = tile < NT;
  if (valid) {
    int g = lane >> 3, c = lane & 7;
    int n = (int)(tile * 16 + th * 8 + g);
    int beg = row_ptr[n];
    int deg = row_ptr[n + 1] - beg;
    float s0 = 0.f, s1 = 0.f, s2 = 0.f, s3 = 0.f;
    int t = 0;
    const int2e* rp = (const int2e*)(recs + beg);
    for (; t + 4 <= deg; t += 4) {
      int2e r0 = __builtin_nontemporal_load(rp + t + 0);
      int2e r1 = __builtin_nontemporal_load(rp + t + 1);
      int2e r2 = __builtin_nontemporal_load(rp + t + 2);
      int2e r3 = __builtin_nontemporal_load(rp + t + 3);
      uint2e q0 = *((const uint2e*)(Y2B + (long long)r0.x * 32) + c);
      uint2e q1 = *((const uint2e*)(Y2B + (long long)r1.x * 32) + c);
      uint2e q2 = *((const uint2e*)(Y2B + (long long)r2.x * 32) + c);
      uint2e q3 = *((const uint2e*)(Y2B + (long long)r3.x * 32) + c);
      s0 += bflo(q0.x) + bflo(q1.x) + bflo(q2.x) + bflo(q3.x);
      s1 += bfhi(q0.x) + bfhi(q1.x) + bfhi(q2.x) + bfhi(q3.x);
      s2 += bflo(q0.y) + bflo(q1.y) + bflo(q2.y) + bflo(q3.y);
      s3 += bfhi(q0.y) + bfhi(q1.y) + bfhi(q2.y) + bfhi(q3.y);
    }
    for (; t < deg; ++t) {
      int2e r = __builtin_nontemporal_load(rp + t);
      uint2e q = *((const uint2e*)(Y2B + (long long)r.x * 32) + c);
      s0 += bflo(q.x); s1 += bfhi(q.x);
      s2 += bflo(q.y); s3 += bfhi(q.y);
    }
    float* sr = &sums[tp][th * 8 + g][c * 4];
    sr[0] = s0; sr[1] = s1; sr[2] = s2; sr[3] = s3;
  }
  __syncthreads();
  if (valid) {
    int m = lane & 15, quad = lane >> 4;
    int bf = flags[1];
    long long n0 = tile * 16;
    const unsigned short* f2 = F2 + (n0 + m) * 96 + quad * 8;
    short8x A[3];
#pragma unroll
    for (int cc = 0; cc < 3; ++cc)
      A[cc] = __builtin_nontemporal_load((const short8x*)(f2 + cc * 32));
    short8x Bf[3];
#pragma unroll
    for (int cc = 0; cc < 3; ++cc)
      Bf[cc] = *(const short8x*)(PK + 12288 + ((cc * 2 + th) * 64 + lane) * 8);
    f32x4 acc;
    float fb = fb2s[th * 16 + m];
#pragma unroll
    for (int i = 0; i < 4; ++i) acc[i] = fb + sums[tp][quad * 4 + i][th * 16 + m];
#pragma unroll
    for (int cc = 0; cc < 3; ++cc)
      acc = __builtin_amdgcn_mfma_f32_16x16x32_bf16(A[cc], Bf[cc], acc, 0, 0, 0);
#pragma unroll
    for (int i = 0; i < 4; ++i) {
      long long idx = (n0 + quad * 4 + i) * 32 + th * 16 + m;
      if (bf) ((unsigned short*)out)[idx] = f2bf(acc[i]);
      else ((float*)out)[idx] = acc[i];
    }
  }
}

extern "C" void kernel_launch(void* const* d_in, const int* in_sizes, int n_in,
                              void* d_out, int out_size, void* d_ws, size_t ws_size,
                              hipStream_t stream) {
  const void* x = d_in[0];
  const void* ei = d_in[1];
  const void* ea = d_in[2];
  const void* W1_msg = d_in[3];
  const void* b1_msg = d_in[4];
  const void* W1_self = d_in[5];
  const void* b1_self = d_in[6];
  const void* gamma = d_in[7];
  const void* beta = d_in[8];
  const void* mean = d_in[9];
  const void* var = d_in[10];
  const void* W2_msg = d_in[11];
  const void* b2_msg = d_in[12];
  const void* W2_self = d_in[13];
  const void* b2_self = d_in[14];

  float* ws = (float*)d_ws;
  int* row_ptr = (int*)(ws + OFF_ROW);
  int2* recs = (int2*)(ws + OFF_RECS);
  int* flags = (int*)(ws + OFF_FLAGS);
  unsigned short* PK = (unsigned short*)(ws + OFF_PK);
  float* fb1s = ws + OFF_FB1S;
  float* fb2s = ws + OFF_FB2S;
  int2* binbuf = (int2*)(ws + OFF_F1);  // 8 MB in the old F1 region
  unsigned short* F2 = (unsigned short*)(ws + OFF_F2);
  unsigned short* Y2B = (unsigned short*)(ws + OFF_Y2B);
  int* bcur = (int*)(ws + OFF_BCUR);

  hipMemsetAsync(bcur, 0, NBK * sizeof(int), stream);
  hipLaunchKernelGGL(k_prepbin, dim3(BINBLK + PREPBLK), dim3(256), 0, stream, ei, x,
                     W1_msg, b1_msg, W1_self, b1_self, gamma, beta, mean, var, W2_msg,
                     b2_msg, W2_self, b2_self, flags, PK, fb1s, fb2s, bcur, binbuf);
  hipLaunchKernelGGL(k_place, dim3(NBK), dim3(1024), 0, stream, bcur, binbuf, row_ptr,
                     recs);

  int fblocks = (NT + 1) / 2;  // 1563 blocks x 4 waves = 6252 waves
  hipLaunchKernelGGL(k_gg1, dim3(fblocks), dim3(256), 0, stream, x, ea, row_ptr, recs,
                     flags, PK, fb1s, F2, Y2B);
  hipLaunchKernelGGL(k_gg2, dim3(fblocks), dim3(256), 0, stream, F2, PK, fb2s, Y2B,
                     row_ptr, recs, flags, d_out);
}

// Round 15
// 206.243 us; speedup vs baseline: 1.0197x; 1.0197x over previous
//
#include <hip/hip_runtime.h>

#define NN 50000
#define NE 800000
#define NT 3125        // NN/16 mfma tiles
#define NBK 256        // coarse buckets (256 -> k_place uses ALL CUs)
#define BNODE 196      // nodes per bucket (196*256 = 50176 >= NN)
#define BCAP 4096      // bucket capacity (mean 3125, +17 sigma)
#define SCAP 26        // per-block LDS stage capacity per bucket (mean 12.2)
#define BINBLK 256     // bin-part blocks in k_prepbin
#define PREPBLK 64     // prep-part blocks in k_prepbin

typedef __attribute__((ext_vector_type(8))) short short8x;
typedef __attribute__((ext_vector_type(4))) float f32x4;

// ws layout (float-index offsets)
#define OFF_ROW   ((long long)NN)     // NN+1 ints (row_ptr)
#define OFF_RECS  (3LL*NN + 16)       // NE int2
#define OFF_FLAGS (35LL*NN + 16)      // ints
#define OFF_PK    (35LL*NN + 256)     // 15360 ushorts (16B-aligned)
#define OFF_FB1S  (35LL*NN + 7936)    // 64 f32
#define OFF_FB2S  (35LL*NN + 8000)    // 32 f32
#define OFF_F1    (36LL*NN)           // binbuf lives here (8 MB < 16 MB region)
#define OFF_F2    (116LL*NN)          // NN*96 bf16
#define OFF_Y2B   (164LL*NN)          // NN*32 bf16
#define OFF_BCUR  (212LL*NN)          // 256 ints

__device__ __forceinline__ float ldf(const void* p, long long i, int bf16) {
  if (bf16) {
    unsigned short u = ((const unsigned short*)p)[i];
    return __uint_as_float(((unsigned)u) << 16);
  }
  return ((const float*)p)[i];
}
__device__ __forceinline__ unsigned short f2bf(float f) {
  unsigned u = __float_as_uint(f);
  unsigned r = (u + 0x7fffu + ((u >> 16) & 1u)) >> 16;
  return (unsigned short)r;
}
__device__ __forceinline__ unsigned pk2(float lo, float hi) {
  return (unsigned)f2bf(lo) | ((unsigned)f2bf(hi) << 16);
}
__device__ __forceinline__ int ldidx(const void* p, long long i, int i64) {
  return i64 ? (int)((const long long*)p)[i] : ((const int*)p)[i];
}
__device__ __forceinline__ float bflo(unsigned u) { return __uint_as_float(u << 16); }
__device__ __forceinline__ float bfhi(unsigned u) { return __uint_as_float(u & 0xffff0000u); }

// ---------------- merged: blocks [0,256) = edge binning; blocks [256,320) = weight prep ----------------
__global__ __launch_bounds__(256) void k_prepbin(
    const void* __restrict__ ei, const void* __restrict__ x,
    const void* __restrict__ W1_msg, const void* __restrict__ b1_msg,
    const void* __restrict__ W1_self, const void* __restrict__ b1_self,
    const void* __restrict__ gamma, const void* __restrict__ beta,
    const void* __restrict__ mean, const void* __restrict__ var,
    const void* __restrict__ W2_msg, const void* __restrict__ b2_msg,
    const void* __restrict__ W2_self, const void* __restrict__ b2_self,
    int* __restrict__ flags, unsigned short* __restrict__ PK,
    float* __restrict__ fb1s, float* __restrict__ fb2s,
    int* __restrict__ bcur, int2* __restrict__ binbuf) {
  int tid = threadIdx.x;
  int lane = tid & 63;
  if (blockIdx.x < BINBLK) {
    // ---- bin body (i64 computed locally; no dependence on flags) ----
    __shared__ int2 stage[NBK][SCAP];  // 53.2 KB
    __shared__ int scnt[NBK];
    __shared__ int gbase[NBK];
    __shared__ int s_i64;
    for (int i = tid; i < NBK; i += 256) scnt[i] = 0;
    if (tid < 64) {
      const int* p = (const int*)ei;
      int any = 0;
      for (int i = lane; i < 256; i += 64) any |= p[2 * i + 1];
      unsigned long long anyb = __ballot(any != 0);
      if (lane == 0) s_i64 = (anyb == 0ull) ? 1 : 0;
    }
    __syncthreads();
    int i64 = s_i64;
    for (long long e0 = (long long)blockIdx.x * 256; e0 < NE;
         e0 += (long long)BINBLK * 256) {
      long long e = e0 + tid;
      if (e < NE) {
        int src = ldidx(ei, e, i64);
        int dst = ldidx(ei, NE + e, i64);
        int b = dst / BNODE;
        int dl = dst - b * BNODE;
        int2 ent = make_int2(src | (dl << 16), (int)e);
        int pos = atomicAdd(&scnt[b], 1);
        if (pos < SCAP) {
          stage[b][pos] = ent;
        } else {  // rare overflow: direct global placement
          int gp = atomicAdd(&bcur[b], 1);
          binbuf[(long long)b * BCAP + gp] = ent;
        }
      }
    }
    __syncthreads();
    if (tid < NBK) {
      int cb = scnt[tid] < SCAP ? scnt[tid] : SCAP;
      gbase[tid] = atomicAdd(&bcur[tid], cb);
    }
    __syncthreads();
    // flush parallelized across the 4 waves
    int wv = tid >> 6, ln = tid & 63;
    for (int b = wv; b < NBK; b += 4) {
      int cb = scnt[b] < SCAP ? scnt[b] : SCAP;
      int gb = gbase[b];
      for (int i = ln; i < cb; i += 64)
        binbuf[(long long)b * BCAP + gb + i] = stage[b][i];
    }
  } else {
    // ---- prep body (runs concurrently with bin; first prep block publishes flags) ----
    __shared__ int s_bf;
    if (tid < 64) {
      const unsigned short* q = (const unsigned short*)x;
      int cntc = 0;
      for (int i = lane; i < 256; i += 64) {
        unsigned short w = q[2 * i];
        int e = (w >> 7) & 0xff;
        if (w == 0 || (e >= 110 && e <= 140)) cntc++;
      }
      for (int m = 1; m < 64; m <<= 1) cntc += __shfl_xor(cntc, m, 64);
      int bfv = (cntc >= 192) ? 1 : 0;
      if (blockIdx.x == BINBLK) {
        const int* p = (const int*)ei;
        int any = 0;
        for (int i = lane; i < 256; i += 64) any |= p[2 * i + 1];
        unsigned long long anyb = __ballot(any != 0);
        if (lane == 0) {
          flags[0] = (anyb == 0ull) ? 1 : 0;
          flags[1] = bfv;
        }
      }
      if (lane == 0) s_bf = bfv;
    }
    __syncthreads();
    int bf = s_bf;
    int t0 = (blockIdx.x - BINBLK) * 256 + tid;
    int stride = PREPBLK * 256;
    for (int i = t0; i < 10240; i += stride) {
      int j = i & 7, L = (i >> 3) & 63, t = (i >> 9) & 3, c = i >> 11;
      int k = c * 32 + ((L >> 4) << 3) + j;
      int col = t * 16 + (L & 15);
      float sc = ldf(gamma, col, bf) * rsqrtf(ldf(var, col, bf) + 1e-5f);
      float v;
      if (k < 64) v = ldf(W1_msg, k * 64 + col, bf) * sc;
      else if (k < 128) v = ldf(W1_self, (k - 64) * 64 + col, bf) * sc;
      else if (k < 144) v = ldf(W1_msg, (64 + k - 128) * 64 + col, bf) * sc;
      else if (k == 144) v = ldf(b1_msg, col, bf) * sc;
      else v = 0.0f;
      PK[i] = f2bf(v);
    }
    for (int i = t0; i < 2048; i += stride) {
      int j = i & 7, L = (i >> 3) & 63, t = (i >> 9) & 1, c = i >> 10;
      int k = c * 32 + ((L >> 4) << 3) + j;
      int col = t * 16 + (L & 15);
      PK[10240 + i] = f2bf(ldf(W2_msg, k * 32 + col, bf));
    }
    for (int i = t0; i < 3072; i += stride) {
      int j = i & 7, L = (i >> 3) & 63, t = (i >> 9) & 1, c = i >> 10;
      int k = c * 32 + ((L >> 4) << 3) + j;
      int col = t * 16 + (L & 15);
      float v;
      if (k < 64) v = ldf(W2_self, k * 32 + col, bf);
      else if (k < 80) v = ldf(W2_msg, k * 32 + col, bf);
      else if (k == 80) v = ldf(b2_msg, col, bf);
      else v = 0.0f;
      PK[12288 + i] = f2bf(v);
    }
    for (int i = t0; i < 64; i += stride) {
      float sc = ldf(gamma, i, bf) * rsqrtf(ldf(var, i, bf) + 1e-5f);
      fb1s[i] = ldf(b1_self, i, bf) * sc + ldf(beta, i, bf) - ldf(mean, i, bf) * sc;
    }
    for (int i = t0; i < 32; i += stride) fb2s[i] = ldf(b2_self, i, bf);
  }
}

// ---------------- phase 2: prefix + histogram + scan + row_ptr + placement ----------------
__global__ __launch_bounds__(1024) void k_place(const int* __restrict__ bcur,
                                                const int2* __restrict__ binbuf,
                                                int* __restrict__ row_ptr,
                                                int2* __restrict__ recs) {
  __shared__ int2 outb[BCAP];  // 32 KB
  __shared__ int lh[BNODE];
  __shared__ int lexc[BNODE];
  __shared__ int lcur[BNODE];
  __shared__ int sb[NBK];
  __shared__ int s_rbase;
  int b = blockIdx.x;
  int tid = threadIdx.x;
  int base = b * BNODE;
  int nn = NN - base < BNODE ? NN - base : BNODE;
  if (tid < NBK) sb[tid] = bcur[tid];
  for (int i = tid; i < BNODE; i += 1024) lh[i] = 0;
  __syncthreads();
  // rbase = exclusive prefix of bucket totals (4 strides of 64 lanes over 256 buckets)
  if (tid < 64) {
    int v = 0;
#pragma unroll
    for (int s = 0; s < 4; ++s) {
      int k = tid + s * 64;
      v += (k < b ? sb[k] : 0);
    }
    for (int off = 32; off > 0; off >>= 1) v += __shfl_down(v, off, 64);
    if (tid == 0) s_rbase = v;
  }
  int cnt = sb[b];
  __syncthreads();
  int rbase = s_rbase;
  // pass 1: local degree histogram
  for (int i = tid; i < cnt; i += 1024) {
    int dl = (binbuf[(long long)b * BCAP + i].x >> 16) & 0x3FF;
    atomicAdd(&lh[dl], 1);
  }
  __syncthreads();
  // wave-0 exclusive scan of lh[0..nn) -> lexc (4 chunks of 64 via shfl)
  if (tid < 64) {
    int carry = 0;
    for (int c0 = 0; c0 < BNODE; c0 += 64) {
      int i = c0 + tid;
      int orig = (i < nn) ? lh[i] : 0;
      int v = orig;
      for (int off = 1; off < 64; off <<= 1) {
        int u = __shfl_up(v, off, 64);
        if (tid >= off) v += u;
      }
      if (i < nn) lexc[i] = carry + v - orig;
      carry += __shfl(v, 63, 64);
    }
  }
  __syncthreads();
  // write row_ptr for this bucket; init placement cursors
  for (int i = tid; i < nn; i += 1024) {
    int e = lexc[i];
    row_ptr[base + i] = rbase + e;
    lcur[i] = e;
  }
  if (b == NBK - 1 && tid == 0) row_ptr[NN] = rbase + cnt;
  __syncthreads();
  // pass 2: placement into LDS at final local offsets
  for (int i = tid; i < cnt; i += 1024) {
    int2 ent = binbuf[(long long)b * BCAP + i];
    int dl = (ent.x >> 16) & 0x3FF;
    int p = atomicAdd(&lcur[dl], 1);
    outb[p] = make_int2(ent.x & 0xFFFF, ent.y);
  }
  __syncthreads();
  // flush: coalesced write of sorted records
  for (int i = tid; i < cnt; i += 1024) recs[rbase + i] = outb[i];
}

// ---------------- fused gather1 + gemm1: 2 waves/tile; gather -> LDS F1-row -> MFMA ----------------
// Gather loop is the proven round-2 body (58 µs floor — do not touch).
__global__ __launch_bounds__(256) void k_gg1(
    const void* __restrict__ x, const void* __restrict__ ea,
    const int* __restrict__ row_ptr, const int2* __restrict__ recs,
    const int* __restrict__ flags, const unsigned short* __restrict__ PK,
    const float* __restrict__ fb1s, unsigned short* __restrict__ F2,
    unsigned short* __restrict__ Y2B) {
  __shared__ __align__(16) unsigned short fs[2][16][168];  // F1-rows, stride 336B (conflict-light)
  __shared__ __align__(16) unsigned short hsh[2][16 * 72]; // h transpose staging
  int tid = threadIdx.x;
  int lane = tid & 63;
  int wv = tid >> 6;
  int tp = wv >> 1, th = wv & 1;
  long long tile = (long long)blockIdx.x * 2 + tp;
  int valid = tile < NT;
  int bf = flags[1];
  int m = lane & 15, quad = lane >> 4;
  if (valid) {
    int g = lane >> 3, c = lane & 7;
    int n = (int)(tile * 16 + th * 8 + g);
    int beg = row_ptr[n];
    int deg = row_ptr[n + 1] - beg;
    float a0 = 0.f, a1 = 0.f, a2 = 0.f, a3 = 0.f, a4 = 0.f, a5 = 0.f, a6 = 0.f, a7 = 0.f;
    float e0 = 0.f, e1 = 0.f, e2 = 0.f, e3 = 0.f;
    uint4 xw;
    if (bf) {
      const unsigned short* xs = (const unsigned short*)x;
      const unsigned short* es = (const unsigned short*)ea;
      int t = 0;
      for (; t + 4 <= deg; t += 4) {
        int2 r0 = recs[beg + t + 0];
        int2 r1 = recs[beg + t + 1];
        int2 r2 = recs[beg + t + 2];
        int2 r3 = recs[beg + t + 3];
        uint4 w0 = *((const uint4*)(xs + ((long long)r0.x << 6)) + c);
        uint4 w1 = *((const uint4*)(xs + ((long long)r1.x << 6)) + c);
        uint4 w2 = *((const uint4*)(xs + ((long long)r2.x << 6)) + c);
        uint4 w3 = *((const uint4*)(xs + ((long long)r3.x << 6)) + c);
        a0 += bflo(w0.x) + bflo(w1.x) + bflo(w2.x) + bflo(w3.x);
        a1 += bfhi(w0.x) + bfhi(w1.x) + bfhi(w2.x) + bfhi(w3.x);
        a2 += bflo(w0.y) + bflo(w1.y) + bflo(w2.y) + bflo(w3.y);
        a3 += bfhi(w0.y) + bfhi(w1.y) + bfhi(w2.y) + bfhi(w3.y);
        a4 += bflo(w0.z) + bflo(w1.z) + bflo(w2.z) + bflo(w3.z);
        a5 += bfhi(w0.z) + bfhi(w1.z) + bfhi(w2.z) + bfhi(w3.z);
        a6 += bflo(w0.w) + bflo(w1.w) + bflo(w2.w) + bflo(w3.w);
        a7 += bfhi(w0.w) + bfhi(w1.w) + bfhi(w2.w) + bfhi(w3.w);
        if (c < 4) {
          uint2 q0 = *((const uint2*)(es + ((long long)r0.y << 4)) + c);
          uint2 q1 = *((const uint2*)(es + ((long long)r1.y << 4)) + c);
          uint2 q2 = *((const uint2*)(es + ((long long)r2.y << 4)) + c);
          uint2 q3 = *((const uint2*)(es + ((long long)r3.y << 4)) + c);
          e0 += bflo(q0.x) + bflo(q1.x) + bflo(q2.x) + bflo(q3.x);
          e1 += bfhi(q0.x) + bfhi(q1.x) + bfhi(q2.x) + bfhi(q3.x);
          e2 += bflo(q0.y) + bflo(q1.y) + bflo(q2.y) + bflo(q3.y);
          e3 += bfhi(q0.y) + bfhi(q1.y) + bfhi(q2.y) + bfhi(q3.y);
        }
      }
      for (; t < deg; ++t) {
        int2 r = recs[beg + t];
        uint4 w = *((const uint4*)(xs + ((long long)r.x << 6)) + c);
        a0 += bflo(w.x); a1 += bfhi(w.x);
        a2 += bflo(w.y); a3 += bfhi(w.y);
        a4 += bflo(w.z); a5 += bfhi(w.z);
        a6 += bflo(w.w); a7 += bfhi(w.w);
        if (c < 4) {
          uint2 q = *((const uint2*)(es + ((long long)r.y << 4)) + c);
          e0 += bflo(q.x); e1 += bfhi(q.x);
          e2 += bflo(q.y); e3 += bfhi(q.y);
        }
      }
      xw = *((const uint4*)(xs + ((long long)n << 6)) + c);
    } else {
      const float* xf = (const float*)x;
      const float* ef = (const float*)ea;
      for (int t = 0; t < deg; ++t) {
        int2 r = recs[beg + t];
        float4 w0 = *((const float4*)(xf + ((long long)r.x << 6)) + c * 2);
        float4 w1 = *((const float4*)(xf + ((long long)r.x << 6)) + c * 2 + 1);
        a0 += w0.x; a1 += w0.y; a2 += w0.z; a3 += w0.w;
        a4 += w1.x; a5 += w1.y; a6 += w1.z; a7 += w1.w;
        if (c < 4) {
          float4 q = *((const float4*)(ef + ((long long)r.y << 4)) + c);
          e0 += q.x; e1 += q.y; e2 += q.z; e3 += q.w;
        }
      }
      float4 p0 = *((const float4*)(xf + ((long long)n << 6)) + c * 2);
      float4 p1 = *((const float4*)(xf + ((long long)n << 6)) + c * 2 + 1);
      xw = make_uint4(pk2(p0.x, p0.y), pk2(p0.z, p0.w), pk2(p1.x, p1.y), pk2(p1.z, p1.w));
    }
    unsigned short* f1 = &fs[tp][th * 8 + g][0];
    unsigned short* f2 = F2 + (long long)n * 96;
    *((uint4*)f1 + c) = make_uint4(pk2(a0, a1), pk2(a2, a3), pk2(a4, a5), pk2(a6, a7));
    *((uint4*)(f1 + 64) + c) = xw;
    if (c < 4) {
      uint2 sp = make_uint2(pk2(e0, e1), pk2(e2, e3));
      *((uint2*)(f1 + 128) + c) = sp;
      *((uint2*)(f2 + 64) + c) = sp;
    }
    if (c == 4) {
      unsigned d = (unsigned)f2bf((float)deg);
      *((uint4*)(f1 + 144)) = make_uint4(d, 0u, 0u, 0u);
      *((uint4*)(f2 + 80)) = make_uint4(d, 0u, 0u, 0u);
    }
    if (c == 5) {
      *((uint4*)(f1 + 152)) = make_uint4(0u, 0u, 0u, 0u);
      *((uint4*)(f2 + 88)) = make_uint4(0u, 0u, 0u, 0u);
    }
  }
  __syncthreads();
  if (valid) {
    long long n0 = tile * 16;
    const unsigned short* f1 = &fs[tp][m][quad * 8];
    short8x A[5];
#pragma unroll
    for (int cc = 0; cc < 5; ++cc) A[cc] = *(const short8x*)(f1 + cc * 32);
    short8x Bf[10];
#pragma unroll
    for (int cc = 0; cc < 5; ++cc)
#pragma unroll
      for (int j = 0; j < 2; ++j)
        Bf[cc * 2 + j] = *(const short8x*)(PK + ((cc * 4 + th * 2 + j) * 64 + lane) * 8);
    f32x4 acc[2];
#pragma unroll
    for (int j = 0; j < 2; ++j) {
      float b = fb1s[(th * 2 + j) * 16 + m];
      acc[j] = (f32x4){b, b, b, b};
    }
#pragma unroll
    for (int cc = 0; cc < 5; ++cc)
#pragma unroll
      for (int j = 0; j < 2; ++j)
        acc[j] = __builtin_amdgcn_mfma_f32_16x16x32_bf16(A[cc], Bf[cc * 2 + j], acc[j], 0, 0, 0);
    // write h to F2 (plain, stays in L2 for gg2) and stage into shared hsh for Y-gemm
    unsigned short* hs = hsh[tp];
#pragma unroll
    for (int j = 0; j < 2; ++j) {
#pragma unroll
      for (int i = 0; i < 4; ++i) {
        float h = fmaxf(acc[j][i], 0.0f);
        unsigned short us = f2bf(h);
        F2[(n0 + quad * 4 + i) * 96 + (th * 2 + j) * 16 + m] = us;
        hs[(quad * 4 + i) * 72 + (th * 2 + j) * 16 + m] = us;
      }
    }
  }
  __syncthreads();
  if (valid) {
    long long n0 = tile * 16;
    const unsigned short* hs = hsh[tp];
    f32x4 yacc = (f32x4){0.f, 0.f, 0.f, 0.f};
#pragma unroll
    for (int cc = 0; cc < 2; ++cc) {
      short8x Ah = *(const short8x*)(hs + m * 72 + cc * 32 + quad * 8);
      short8x By = *(const short8x*)(PK + 10240 + ((cc * 2 + th) * 64 + lane) * 8);
      yacc = __builtin_amdgcn_mfma_f32_16x16x32_bf16(Ah, By, yacc, 0, 0, 0);
    }
#pragma unroll
    for (int i = 0; i < 4; ++i)
      Y2B[(n0 + quad * 4 + i) * 32 + th * 16 + m] = f2bf(yacc[i]);
  }
}

// ---------------- fused gather2 + gemm2: 4 lanes/node x uint4 (full 64B row); the tile's
// 2 waves split each node's edge list in half -> per-wave serial trips halve at unchanged
// TLP. Partials staged in 16B-ALIGNED LDS (the r13/r14 version lacked __align__(16) on a
// float4-stored LDS array — the one identified UB; fixed here). ----------------
__global__ __launch_bounds__(256) void k_gg2(
    const unsigned short* __restrict__ F2, const unsigned short* __restrict__ PK,
    const float* __restrict__ fb2s, const unsigned short* __restrict__ Y2B,
    const int* __restrict__ row_ptr, const int2* __restrict__ recs,
    const int* __restrict__ flags, void* __restrict__ out) {
  __shared__ __align__(16) float sums[2][2][16][36];  // [pair][edge-half][row][32ch pad] 9.2 KB
  int tid = threadIdx.x;
  int lane = tid & 63;
  int wv = tid >> 6;
  int tp = wv >> 1;
  int th = wv & 1;
  long long tile = (long long)blockIdx.x * 2 + tp;
  int valid = tile < NT;
  if (valid) {
    int g = lane >> 2, c = lane & 3;  // 16 nodes/wave, 4 lanes/node, 16B/lane
    int n = (int)(tile * 16 + g);
    int beg = row_ptr[n];
    int deg = row_ptr[n + 1] - beg;
    int dh = deg >> 1;
    int tb = th ? dh : 0;
    int te = th ? deg : dh;
    float s0 = 0.f, s1 = 0.f, s2 = 0.f, s3 = 0.f, s4 = 0.f, s5 = 0.f, s6 = 0.f, s7 = 0.f;
    int t = tb;
    for (; t + 4 <= te; t += 4) {
      int2 r0 = recs[beg + t + 0];
      int2 r1 = recs[beg + t + 1];
      int2 r2 = recs[beg + t + 2];
      int2 r3 = recs[beg + t + 3];
      uint4 w0 = *((const uint4*)(Y2B + (long long)r0.x * 32) + c);
      uint4 w1 = *((const uint4*)(Y2B + (long long)r1.x * 32) + c);
      uint4 w2 = *((const uint4*)(Y2B + (long long)r2.x * 32) + c);
      uint4 w3 = *((const uint4*)(Y2B + (long long)r3.x * 32) + c);
      s0 += bflo(w0.x) + bflo(w1.x) + bflo(w2.x) + bflo(w3.x);
      s1 += bfhi(w0.x) + bfhi(w1.x) + bfhi(w2.x) + bfhi(w3.x);
      s2 += bflo(w0.y) + bflo(w1.y) + bflo(w2.y) + bflo(w3.y);
      s3 += bfhi(w0.y) + bfhi(w1.y) + bfhi(w2.y) + bfhi(w3.y);
      s4 += bflo(w0.z) + bflo(w1.z) + bflo(w2.z) + bflo(w3.z);
      s5 += bfhi(w0.z) + bfhi(w1.z) + bfhi(w2.z) + bfhi(w3.z);
      s6 += bflo(w0.w) + bflo(w1.w) + bflo(w2.w) + bflo(w3.w);
      s7 += bfhi(w0.w) + bfhi(w1.w) + bfhi(w2.w) + bfhi(w3.w);
    }
    for (; t < te; ++t) {
      int2 r = recs[beg + t];
      uint4 w = *((const uint4*)(Y2B + (long long)r.x * 32) + c);
      s0 += bflo(w.x); s1 += bfhi(w.x);
      s2 += bflo(w.y); s3 += bfhi(w.y);
      s4 += bflo(w.z); s5 += bfhi(w.z);
      s6 += bflo(w.w); s7 += bfhi(w.w);
    }
    float* sr = &sums[tp][th][g][c * 8];
    *(f32x4*)(sr) = (f32x4){s0, s1, s2, s3};
    *(f32x4*)(sr + 4) = (f32x4){s4, s5, s6, s7};
  }
  __syncthreads();
  if (valid) {
    int m = lane & 15, quad = lane >> 4;
    int bf = flags[1];
    long long n0 = tile * 16;
    const unsigned short* f2 = F2 + (n0 + m) * 96 + quad * 8;
    short8x A[3];
#pragma unroll
    for (int cc = 0; cc < 3; ++cc) A[cc] = *(const short8x*)(f2 + cc * 32);
    short8x Bf[3];
#pragma unroll
    for (int cc = 0; cc < 3; ++cc)
      Bf[cc] = *(const short8x*)(PK + 12288 + ((cc * 2 + th) * 64 + lane) * 8);
    f32x4 acc;
    float fb = fb2s[th * 16 + m];
#pragma unroll
    for (int i = 0; i < 4; ++i)
      acc[i] = fb + sums[tp][0][quad * 4 + i][th * 16 + m] +
               sums[tp][1][quad * 4 + i][th * 16 + m];
#pragma unroll
    for (int cc = 0; cc < 3; ++cc)
      acc = __builtin_amdgcn_mfma_f32_16x16x32_bf16(A[cc], Bf[cc], acc, 0, 0, 0);
#pragma unroll
    for (int i = 0; i < 4; ++i) {
      long long idx = (n0 + quad * 4 + i) * 32 + th * 16 + m;
      if (bf) ((unsigned short*)out)[idx] = f2bf(acc[i]);
      else ((float*)out)[idx] = acc[i];
    }
  }
}

extern "C" void kernel_launch(void* const* d_in, const int* in_sizes, int n_in,
                              void* d_out, int out_size, void* d_ws, size_t ws_size,
                              hipStream_t stream) {
  const void* x = d_in[0];
  const void* ei = d_in[1];
  const void* ea = d_in[2];
  const void* W1_msg = d_in[3];
  const void* b1_msg = d_in[4];
  const void* W1_self = d_in[5];
  const void* b1_self = d_in[6];
  const void* gamma = d_in[7];
  const void* beta = d_in[8];
  const void* mean = d_in[9];
  const void* var = d_in[10];
  const void* W2_msg = d_in[11];
  const void* b2_msg = d_in[12];
  const void* W2_self = d_in[13];
  const void* b2_self = d_in[14];

  float* ws = (float*)d_ws;
  int* row_ptr = (int*)(ws + OFF_ROW);
  int2* recs = (int2*)(ws + OFF_RECS);
  int* flags = (int*)(ws + OFF_FLAGS);
  unsigned short* PK = (unsigned short*)(ws + OFF_PK);
  float* fb1s = ws + OFF_FB1S;
  float* fb2s = ws + OFF_FB2S;
  int2* binbuf = (int2*)(ws + OFF_F1);  // 8 MB in the old F1 region
  unsigned short* F2 = (unsigned short*)(ws + OFF_F2);
  unsigned short* Y2B = (unsigned short*)(ws + OFF_Y2B);
  int* bcur = (int*)(ws + OFF_BCUR);

  hipMemsetAsync(bcur, 0, NBK * sizeof(int), stream);
  hipLaunchKernelGGL(k_prepbin, dim3(BINBLK + PREPBLK), dim3(256), 0, stream, ei, x,
                     W1_msg, b1_msg, W1_self, b1_self, gamma, beta, mean, var, W2_msg,
                     b2_msg, W2_self, b2_self, flags, PK, fb1s, fb2s, bcur, binbuf);
  hipLaunchKernelGGL(k_place, dim3(NBK), dim3(1024), 0, stream, bcur, binbuf, row_ptr,
                     recs);

  int fblocks = (NT + 1) / 2;  // 1563 blocks x 4 waves = 6252 waves
  hipLaunchKernelGGL(k_gg1, dim3(fblocks), dim3(256), 0, stream, x, ea, row_ptr, recs,
                     flags, PK, fb1s, F2, Y2B);
  hipLaunchKernelGGL(k_gg2, dim3(fblocks), dim3(256), 0, stream, F2, PK, fb2s, Y2B,
                     row_ptr, recs, flags, d_out);
}